// Round 5
// baseline (7647.706 us; speedup 1.0000x reference)
//
#include <hip/hip_runtime.h>
#include <hip/hip_bf16.h>
#include <math.h>

// ---------------- problem constants ----------------
#define NIMG 8
#define NPX 4096          // 64*64 pixels per image
#define NA 9
#define NANCH 36864       // NPX*NA
#define PRE 2000
#define POST 300

#define KEY_NEGINF 0x000FFFFFFFFFFFFFULL   // monotone key of -inf

// per-image ws sizes (bytes)
#define SZ_XPAD1 (512ULL*66*66*4)      // 8,921,088  fp32 padded CHW
#define SZ_H1    (4096ULL*512*8)       // 16,777,216 fp64 h

// ---------------- K1a: conv1_w [oc][ic][3][3] fp32 -> wt [s][ic][oc] fp32 ----------------
__global__ void wt_kernel(const float* __restrict__ w, float* __restrict__ wt) {
  int idx = blockIdx.x * 256 + threadIdx.x;
  if (idx >= 9 * 512 * 512) return;
  int oc = idx & 511;
  int ic = (idx >> 9) & 511;
  int s  = idx >> 18;
  wt[idx] = w[((size_t)(oc * 512 + ic)) * 9 + s];
}

// ---------------- K1b: pad copy x NCHW fp32 -> xpad [nl][512][66][66] fp32 ----------------
__global__ void pad_kernel(const float* __restrict__ x, float* __restrict__ xp) {
  const int y = blockIdx.x * 4 + (threadIdx.x >> 6);
  const int xcol = threadIdx.x & 63;
  const int c = blockIdx.y, nl = blockIdx.z;
  xp[(((size_t)nl * 512 + c) * 66 + (y + 1)) * 66 + 1 + xcol] =
      x[(((size_t)nl * 512 + c) * 64 + y) * 64 + xcol];
}

// ---------------- K2: 3x3 conv, fp64 implicit GEMM (64px x 64oc tile) ----------------
__global__ __launch_bounds__(256) void conv3_f64(
    const float* __restrict__ xp, const float* __restrict__ wt,
    const float* __restrict__ bias, double* __restrict__ h) {
  __shared__ double As[64][33];   // [x][k]
  __shared__ double Bs[64][33];   // [oc][k]
  const int octile = blockIdx.x, ytile = blockIdx.y, nl = blockIdx.z;
  const int tid = threadIdx.x;
  const int tx = tid & 15, ty = tid >> 4;
  const int sx = tid & 63, sg = tid >> 6;   // staging: column, k-group

  double acc[4][4];
#pragma unroll
  for (int i = 0; i < 4; ++i)
#pragma unroll
    for (int j = 0; j < 4; ++j) acc[i][j] = 0.0;

  for (int s = 0; s < 9; ++s) {
    const int ky = s / 3, kx = s - ky * 3;
    const float* xsrc = xp + ((size_t)nl * 512) * 4356 + (size_t)(ytile + ky) * 66 + kx;
    const float* wsrc = wt + (size_t)s * 262144 + octile * 64;
    for (int icb = 0; icb < 16; ++icb) {
      __syncthreads();
#pragma unroll
      for (int j = 0; j < 8; ++j) {
        const int kl = sg * 8 + j;
        const int ic = icb * 32 + kl;
        As[sx][kl] = (double)xsrc[(size_t)ic * 4356 + sx];
        Bs[sx][kl] = (double)wsrc[(size_t)ic * 512 + sx];
      }
      __syncthreads();
#pragma unroll 4
      for (int k = 0; k < 32; ++k) {
        double a0 = As[ty * 4 + 0][k], a1 = As[ty * 4 + 1][k],
               a2 = As[ty * 4 + 2][k], a3 = As[ty * 4 + 3][k];
        double b0 = Bs[tx * 4 + 0][k], b1 = Bs[tx * 4 + 1][k],
               b2 = Bs[tx * 4 + 2][k], b3 = Bs[tx * 4 + 3][k];
        acc[0][0] += a0 * b0; acc[0][1] += a0 * b1; acc[0][2] += a0 * b2; acc[0][3] += a0 * b3;
        acc[1][0] += a1 * b0; acc[1][1] += a1 * b1; acc[1][2] += a1 * b2; acc[1][3] += a1 * b3;
        acc[2][0] += a2 * b0; acc[2][1] += a2 * b1; acc[2][2] += a2 * b2; acc[2][3] += a2 * b3;
        acc[3][0] += a3 * b0; acc[3][1] += a3 * b1; acc[3][2] += a3 * b2; acc[3][3] += a3 * b3;
      }
    }
  }
  // epilogue: +bias, relu, store h[(nl*4096 + p)*512 + oc]
#pragma unroll
  for (int i = 0; i < 4; ++i) {
    const int p = ytile * 64 + ty * 4 + i;
    double* hrow = h + ((size_t)nl * 4096 + p) * 512 + octile * 64;
#pragma unroll
    for (int j = 0; j < 4; ++j) {
      const int oc = tx * 4 + j;
      double v = acc[i][j] + (double)bias[octile * 64 + oc];
      hrow[oc] = v > 0.0 ? v : 0.0;
    }
  }
}

// ---------------- K3: head (fp64) + decode + keys ----------------
// anchor corner constants as np.float32 values (promoted to f64 in use)
__device__ __constant__ float AC0[9] = {-37.254833996f, -82.509667992f, -173.019335984f,
                                        -56.f, -120.f, -248.f,
                                        -82.509667992f, -173.019335984f, -354.038671968f};
__device__ __constant__ float AC1[9] = {-82.509667992f, -173.019335984f, -354.038671968f,
                                        -56.f, -120.f, -248.f,
                                        -37.254833996f, -82.509667992f, -173.019335984f};
__device__ __constant__ float AC2[9] = {53.254833996f, 98.509667992f, 189.019335984f,
                                        72.f, 136.f, 264.f,
                                        98.509667992f, 189.019335984f, 370.038671968f};
__device__ __constant__ float AC3[9] = {98.509667992f, 189.019335984f, 370.038671968f,
                                        72.f, 136.f, 264.f,
                                        53.254833996f, 98.509667992f, 189.019335984f};

__global__ __launch_bounds__(256) void head_f64(
    const double* __restrict__ h,
    const float* __restrict__ sw, const float* __restrict__ sb,
    const float* __restrict__ lw, const float* __restrict__ lb,
    const int* __restrict__ imh, const int* __restrict__ imw,
    float* __restrict__ out_locs, float* __restrict__ out_scores,
    double* __restrict__ boxes, unsigned long long* __restrict__ ckeys, int base_n) {
  __shared__ double Wsh[128 * 54];   // [cc][o], 55.3 KB
  const int tid = threadIdx.x;
  const int gp = blockIdx.x * 256 + tid;   // chunk-local pixel
  const int nl = gp >> 12, p = gp & 4095;
  const int n = base_n + nl;

  double acc[54];
#pragma unroll
  for (int o = 0; o < 54; ++o) acc[o] = 0.0;

  for (int cb = 0; cb < 4; ++cb) {
    const int cbase = cb * 128;
    __syncthreads();
    for (int idx = tid; idx < 128 * 54; idx += 256) {
      int cc = idx / 54;
      int o  = idx - cc * 54;
      int c  = cbase + cc;
      float wv = (o < 18) ? sw[o * 512 + c] : lw[(o - 18) * 512 + c];
      Wsh[idx] = (double)wv;
    }
    __syncthreads();
    const double* hp = h + (size_t)gp * 512 + cbase;
    for (int cc = 0; cc < 128; ++cc) {
      double hv = hp[cc];
      const double2* wp = (const double2*)&Wsh[cc * 54];
#pragma unroll
      for (int oo = 0; oo < 27; ++oo) {
        double2 w2 = wp[oo];
        acc[oo * 2]     += w2.x * hv;
        acc[oo * 2 + 1] += w2.y * hv;
      }
    }
  }

  double sc[18], lcv[36];
#pragma unroll
  for (int j = 0; j < 18; ++j) sc[j] = acc[j] + (double)sb[j];
#pragma unroll
  for (int j = 0; j < 36; ++j) lcv[j] = acc[18 + j] + (double)lb[j];

  // continuous outputs (fp32)
  {
    size_t lo = (size_t)n * 147456 + (size_t)p * 36;
#pragma unroll
    for (int j = 0; j < 36; ++j) out_locs[lo + j] = (float)lcv[j];
    size_t so = (size_t)n * 73728 + (size_t)p * 18;
#pragma unroll
    for (int j = 0; j < 18; ++j) out_scores[so + j] = (float)sc[j];
  }

  // decode / clip / size-filter / key (all fp64, np op order)
  const double Hc = (double)imh[0], Wc = (double)imw[0];
  const double ys = (double)(p >> 6) * 16.0;
  const double xs = (double)(p & 63) * 16.0;
#pragma unroll
  for (int a = 0; a < 9; ++a) {
    // anchors are fp32 values (np.float32 in reference) promoted to f64:
    double a0 = (double)(float)((float)ys + AC0[a]);
    double a1 = (double)(float)((float)xs + AC1[a]);
    double a2 = (double)(float)((float)ys + AC2[a]);
    double a3 = (double)(float)((float)xs + AC3[a]);
    double ah = a2 - a0, aw = a3 - a1;
    double acy = a0 + 0.5 * ah;
    double acx = a1 + 0.5 * aw;
    double dy = lcv[a * 4 + 0], dx = lcv[a * 4 + 1], dh = lcv[a * 4 + 2], dw = lcv[a * 4 + 3];
    double cy = dy * ah + acy;
    double cx = dx * aw + acx;
    double bh = exp(dh) * ah;
    double bw = exp(dw) * aw;
    double y0 = cy - 0.5 * bh, x0 = cx - 0.5 * bw;
    double y1 = cy + 0.5 * bh, x1 = cx + 0.5 * bw;
    y0 = fmin(fmax(y0, 0.0), Hc); x0 = fmin(fmax(x0, 0.0), Wc);
    y1 = fmin(fmax(y1, 0.0), Hc); x1 = fmin(fmax(x1, 0.0), Wc);
    bool valid = ((y1 - y0) >= 16.0) && ((x1 - x0) >= 16.0);
    int bi = p * 9 + a;
    double* bq = boxes + ((size_t)n * NANCH + bi) * 4;
    bq[0] = y0; bq[1] = x0; bq[2] = y1; bq[3] = x1;
    double fgm = valid ? sc[a * 2 + 1] : -HUGE_VAL;
    unsigned long long u = (unsigned long long)__double_as_longlong(fgm);
    unsigned long long key = (u >> 63) ? ~u : (u | 0x8000000000000000ULL);
    ckeys[(size_t)n * NANCH + bi] = key;
  }
}

// ---------------- K4: radix-select pivot (64-bit) + bitonic sort top-2000 ----------------
__global__ __launch_bounds__(1024) void topk_kernel(
    const unsigned long long* __restrict__ ckeys, const double* __restrict__ boxes,
    double* __restrict__ bsort, int* __restrict__ fin) {
  __shared__ unsigned int hist[256];
  __shared__ unsigned long long srtk[2048];
  __shared__ int srti[2048];
  __shared__ unsigned long long Psh;
  __shared__ int tsh, cnt;
  const int n = blockIdx.x, tid = threadIdx.x;
  const unsigned long long* ck = ckeys + (size_t)n * NANCH;
  if (tid == 0) { tsh = PRE; Psh = 0ULL; }
  __syncthreads();
  for (int byte = 7; byte >= 0; --byte) {
    if (tid < 256) hist[tid] = 0u;
    __syncthreads();
    const int sh = byte * 8;
    const unsigned long long pref = Psh;
    for (int i = tid; i < NANCH; i += 1024) {
      unsigned long long v = ck[i];
      bool ok = (byte == 7) || ((v >> (sh + 8)) == pref);
      if (ok) atomicAdd(&hist[(unsigned)(v >> sh) & 255u], 1u);
    }
    __syncthreads();
    if (tid == 0) {
      int t = tsh, cum = 0, bsel = 0;
      for (int b = 255; b >= 0; --b) {
        int c = (int)hist[b];
        if (cum + c >= t) { bsel = b; tsh = t - cum; break; }
        cum += c;
      }
      Psh = (Psh << 8) | (unsigned long long)(unsigned)bsel;
    }
    __syncthreads();
  }
  const unsigned long long P = Psh;
  if (tid == 0) cnt = 0;
  for (int i = tid; i < 2048; i += 1024) { srtk[i] = 0ULL; srti[i] = 0; }
  __syncthreads();
  for (int i = tid; i < NANCH; i += 1024) {
    unsigned long long v = ck[i];
    if (v >= P) {
      int pos = atomicAdd(&cnt, 1);
      if (pos < 2048) { srtk[pos] = v; srti[pos] = i; }
    }
  }
  __syncthreads();
  // bitonic sort descending on keys (unique; pads=0 sort last)
  for (int k = 2; k <= 2048; k <<= 1) {
    for (int j = k >> 1; j > 0; j >>= 1) {
      for (int idx = tid; idx < 2048; idx += 1024) {
        int pr = idx ^ j;
        if (pr > idx) {
          unsigned long long a = srtk[idx], b = srtk[pr];
          bool up = (idx & k) == 0;
          if (up ? (a < b) : (a > b)) {
            srtk[idx] = b; srtk[pr] = a;
            int ti = srti[idx]; srti[idx] = srti[pr]; srti[pr] = ti;
          }
        }
      }
      __syncthreads();
    }
  }
  // gather boxes (f64) + finite flags
  const double* bsrc = boxes + (size_t)n * NANCH * 4;
  double* bdst = bsort + (size_t)n * 2048 * 4;
  for (int r = tid; r < PRE; r += 1024) {
    int bi = srti[r];
    fin[n * 2048 + r] = (srtk[r] > KEY_NEGINF) ? 1 : 0;
    bdst[r * 4 + 0] = bsrc[(size_t)bi * 4 + 0];
    bdst[r * 4 + 1] = bsrc[(size_t)bi * 4 + 1];
    bdst[r * 4 + 2] = bsrc[(size_t)bi * 4 + 2];
    bdst[r * 4 + 3] = bsrc[(size_t)bi * 4 + 3];
  }
}

// ---------------- K5: suppression bitmasks, fp64 IoU (np op order) ----------------
__global__ __launch_bounds__(256) void mask_kernel(
    const double* __restrict__ bsort, unsigned long long* __restrict__ masks) {
  __shared__ double bb[PRE * 4];   // 64 KB
  const int ib = blockIdx.x, n = blockIdx.y;
  const double2* src = (const double2*)(bsort + (size_t)n * 2048 * 4);
  for (int i = threadIdx.x; i < PRE * 2; i += 256) ((double2*)bb)[i] = src[i];
  __syncthreads();
  const int i = ib * 64 + (threadIdx.x >> 2);
  if (i >= PRE) return;
  const double ay0 = bb[i * 4], ax0 = bb[i * 4 + 1], ay1 = bb[i * 4 + 2], ax1 = bb[i * 4 + 3];
  const double aarea = (ay1 - ay0) * (ax1 - ax0);
  unsigned long long* mrow = masks + ((size_t)n * 2048 + i) * 32;
#pragma unroll
  for (int k = 0; k < 8; ++k) {
    const int w = (threadIdx.x & 3) + k * 4;
    unsigned long long m = 0ULL;
    for (int b = 0; b < 64; ++b) {
      int j = w * 64 + b;
      if (j < PRE) {
        double by0 = bb[j * 4], bx0 = bb[j * 4 + 1], by1 = bb[j * 4 + 2], bx1 = bb[j * 4 + 3];
        double ty = fmax(ay0, by0), tx = fmax(ax0, bx0);
        double ry = fmin(ay1, by1), rx = fmin(ax1, bx1);
        double ih = fmax(ry - ty, 0.0);
        double iw = fmax(rx - tx, 0.0);
        double inter = ih * iw;
        double barea = (by1 - by0) * (bx1 - bx0);
        double iou = inter / (aarea + barea - inter + 1e-9);
        if (iou > 0.7) m |= (1ULL << b);
      }
    }
    mrow[w] = m;
  }
}

// ---------------- K6: greedy scan, first-300-kept, write rois fp32 ----------------
__global__ void scan_kernel(const unsigned long long* __restrict__ masks,
                            const double* __restrict__ bsort, const int* __restrict__ fin,
                            float* __restrict__ out_rois, float* __restrict__ out_inds) {
  const int n = blockIdx.x, lane = threadIdx.x;
  const unsigned long long* mrow = masks + (size_t)n * 2048 * 32;
  unsigned long long rem = 0ULL;
  if (lane < 32) {
    unsigned long long fw = 0ULL;
    for (int b = 0; b < 64; ++b) {
      int i = (lane << 6) + b;
      if (i < PRE && fin[n * 2048 + i]) fw |= (1ULL << b);
    }
    rem = ~fw;
  }
  __shared__ int kept[POST];
  int kcnt = 0;
  for (int i = 0; i < PRE; ++i) {
    unsigned long long w = __shfl(rem, i >> 6);
    if (!((w >> (i & 63)) & 1ULL)) {
      if (lane == 0 && kcnt < POST) kept[kcnt] = i;
      ++kcnt;
      if (kcnt == POST) break;
      if (lane < 32) rem |= mrow[(size_t)i * 32 + lane];
    }
  }
  __syncthreads();
  const double* bs = bsort + (size_t)n * 2048 * 4;
  for (int r = lane; r < POST; r += 64) {
    double b0 = 0, b1 = 0, b2 = 0, b3 = 0;
    if (r < kcnt) {
      const double* q = bs + (size_t)kept[r] * 4;
      b0 = q[0]; b1 = q[1]; b2 = q[2]; b3 = q[3];
    }
    size_t o = ((size_t)n * POST + r) * 4;
    out_rois[o + 0] = (float)b0;
    out_rois[o + 1] = (float)b1;
    out_rois[o + 2] = (float)b2;
    out_rois[o + 3] = (float)b3;
    out_inds[n * POST + r] = (float)n;
  }
}

// ---------------- launch ----------------
extern "C" void kernel_launch(void* const* d_in, const int* in_sizes, int n_in,
                              void* d_out, int out_size, void* d_ws, size_t ws_size,
                              hipStream_t stream) {
  const float* x   = (const float*)d_in[0];
  const float* c1w = (const float*)d_in[1];
  const float* c1b = (const float*)d_in[2];
  const float* sw  = (const float*)d_in[3];
  const float* sb  = (const float*)d_in[4];
  const float* lw  = (const float*)d_in[5];
  const float* lb  = (const float*)d_in[6];
  const int* imh = (const int*)d_in[7];
  const int* imw = (const int*)d_in[8];
  float* out = (float*)d_out;

  // fixed ws ~26.0 MB; per-image (xpad f32 + h f64) ~25.7 MB
  int G = (ws_size >= 235000000ULL) ? 8
        : (ws_size >= 131000000ULL) ? 4
        : (ws_size >=  79000000ULL) ? 2 : 1;

  char* ws = (char*)d_ws;
  size_t off = 0;
  float* wtb   = (float*)(ws + off);  off += 9ULL * 512 * 512 * 4;
  float* xpad  = (float*)(ws + off);  off += (size_t)G * SZ_XPAD1;
  double* hbuf = (double*)(ws + off); off += (size_t)G * SZ_H1;
  double* boxes = (double*)(ws + off); off += 8ULL * NANCH * 4 * 8;
  unsigned long long* ckeys = (unsigned long long*)(ws + off); off += 8ULL * NANCH * 8;
  double* bsortd = (double*)(ws + off); off += 8ULL * 2048 * 4 * 8;
  int* fin = (int*)(ws + off); off += 8ULL * 2048 * 4;
  unsigned long long* masks = (unsigned long long*)(ws + off); off += 8ULL * 2048 * 32 * 8;

  float* out_locs   = out;                 // 8*36864*4
  float* out_scores = out + 1179648;       // 8*36864*2
  float* out_rois   = out + 1769472;       // 2400*4
  float* out_inds   = out + 1779072;       // 2400

  hipMemsetAsync(xpad, 0, (size_t)G * SZ_XPAD1, stream);
  wt_kernel<<<9216, 256, 0, stream>>>(c1w, wtb);
  for (int c = 0; c < NIMG / G; ++c) {
    pad_kernel<<<dim3(16, 512, G), 256, 0, stream>>>(x + (size_t)c * G * 512 * 4096, xpad);
    conv3_f64<<<dim3(8, 64, G), 256, 0, stream>>>(xpad, wtb, c1b, hbuf);
    head_f64<<<16 * G, 256, 0, stream>>>(hbuf, sw, sb, lw, lb, imh, imw,
                                         out_locs, out_scores, boxes, ckeys, c * G);
  }
  topk_kernel<<<8, 1024, 0, stream>>>(ckeys, boxes, bsortd, fin);
  mask_kernel<<<dim3(32, 8), 256, 0, stream>>>(bsortd, masks);
  scan_kernel<<<8, 64, 0, stream>>>(masks, bsortd, fin, out_rois, out_inds);
}

// Round 6
// 4114.755 us; speedup vs baseline: 1.8586x; 1.8586x over previous
//
#include <hip/hip_runtime.h>
#include <hip/hip_bf16.h>
#include <math.h>

// ---------------- problem constants ----------------
#define NIMG 8
#define NPX 4096          // 64*64 pixels per image
#define NA 9
#define NANCH 36864       // NPX*NA
#define PRE 2000
#define POST 300

#define KEY_NEGINF 0x000FFFFFFFFFFFFFULL   // monotone key of -inf

// per-image ws sizes (bytes)
#define SZ_XPAD1 (512ULL*66*66*4)      // 8,921,088  fp32 padded CHW
#define SZ_H1    (4096ULL*512*8)       // 16,777,216 fp64 h

// ---------------- K1a: conv1_w [oc][ic][3][3] fp32 -> wt [s][ic][oc] fp32 ----------------
__global__ void wt_kernel(const float* __restrict__ w, float* __restrict__ wt) {
  int idx = blockIdx.x * 256 + threadIdx.x;
  if (idx >= 9 * 512 * 512) return;
  int oc = idx & 511;
  int ic = (idx >> 9) & 511;
  int s  = idx >> 18;
  wt[idx] = w[((size_t)(oc * 512 + ic)) * 9 + s];
}

// ---------------- K1b: pad copy x NCHW fp32 -> xpad [nl][512][66][66] fp32 ----------------
__global__ void pad_kernel(const float* __restrict__ x, float* __restrict__ xp) {
  const int y = blockIdx.x * 4 + (threadIdx.x >> 6);
  const int xcol = threadIdx.x & 63;
  const int c = blockIdx.y, nl = blockIdx.z;
  xp[(((size_t)nl * 512 + c) * 66 + (y + 1)) * 66 + 1 + xcol] =
      x[(((size_t)nl * 512 + c) * 64 + y) * 64 + xcol];
}

// ---------------- K2: 3x3 conv, fp64 implicit GEMM, 64px x 128oc tile ----------------
// 256 threads; per thread 4 px x 8 oc acc (oc set {2tx+32j, 2tx+1+32j}).
// LDS: As[k][px] (+2 pad), Bs[k][oc] (+2 pad) -> all reads <=2-way bank aliasing.
// Summation order (s asc, ic asc, fused FMA) identical to the R5 kernel -> h bitwise same.
__global__ __launch_bounds__(256, 4) void conv3_f64(
    const float* __restrict__ xp, const float* __restrict__ wt,
    const float* __restrict__ bias, double* __restrict__ h) {
  __shared__ double As[16][66];    // 8448 B
  __shared__ double Bs[16][130];   // 16640 B
  const int octile = blockIdx.x;   // 0..3  (128 oc each)
  const int y      = blockIdx.y;   // 0..63 (one 64-px image row)
  const int nl     = blockIdx.z;
  const int tid = threadIdx.x;
  const int tx  = tid & 15;        // oc lane
  const int ty4 = (tid >> 4) << 2; // px base (4 px)
  const int sk  = tid >> 4;        // staging k row 0..15
  const int sa  = (tid & 15) << 2; // staging A px base (4 px)
  const int sb  = (tid & 15) << 3; // staging B oc base (8 oc)
  const int ocg0 = octile << 7;

  double acc[4][8];
#pragma unroll
  for (int i = 0; i < 4; ++i)
#pragma unroll
    for (int j = 0; j < 8; ++j) acc[i][j] = 0.0;

  // prologue: load it=0 staging regs
  float a0, a1, a2, a3; float4 b0, b1;
  {
    const float* xs2 = xp + ((size_t)(nl * 512 + sk)) * 4356 + (size_t)y * 66 + sa;
    a0 = xs2[0]; a1 = xs2[1]; a2 = xs2[2]; a3 = xs2[3];
    const float* ws2 = wt + (size_t)sk * 512 + ocg0 + sb;
    b0 = *(const float4*)ws2; b1 = *(const float4*)(ws2 + 4);
  }

  for (int it = 0; it < 288; ++it) {          // it = s*32 + icb
    __syncthreads();                          // previous compute done
    // stage regs -> LDS (double2, aligned, conflict-light)
    {
      double2* aw = (double2*)&As[sk][sa];
      aw[0] = make_double2((double)a0, (double)a1);
      aw[1] = make_double2((double)a2, (double)a3);
      double2* bw = (double2*)&Bs[sk][sb];
      bw[0] = make_double2((double)b0.x, (double)b0.y);
      bw[1] = make_double2((double)b0.z, (double)b0.w);
      bw[2] = make_double2((double)b1.x, (double)b1.y);
      bw[3] = make_double2((double)b1.z, (double)b1.w);
    }
    __syncthreads();                          // tile visible
    // preload next iteration's staging regs (lands during compute)
    {
      const int jt = (it + 1 < 288) ? it + 1 : 287;
      const int s = jt >> 5, icb = jt & 31;
      const int ky = s / 3, kx = s - ky * 3;
      const int ic = (icb << 4) + sk;
      const float* xs2 = xp + ((size_t)(nl * 512 + ic)) * 4356 +
                         (size_t)(y + ky) * 66 + kx + sa;
      a0 = xs2[0]; a1 = xs2[1]; a2 = xs2[2]; a3 = xs2[3];
      const float* ws2 = wt + (size_t)s * 262144 + (size_t)ic * 512 + ocg0 + sb;
      b0 = *(const float4*)ws2; b1 = *(const float4*)(ws2 + 4);
    }
    // compute 16 k-steps
#pragma unroll
    for (int k = 0; k < 16; ++k) {
      const double2* ap = (const double2*)&As[k][ty4];
      double2 A01 = ap[0], A23 = ap[1];
#pragma unroll
      for (int j = 0; j < 4; ++j) {
        double2 B2 = *(const double2*)&Bs[k][(tx << 1) + (j << 5)];
        acc[0][2 * j]     += A01.x * B2.x;
        acc[0][2 * j + 1] += A01.x * B2.y;
        acc[1][2 * j]     += A01.y * B2.x;
        acc[1][2 * j + 1] += A01.y * B2.y;
        acc[2][2 * j]     += A23.x * B2.x;
        acc[2][2 * j + 1] += A23.x * B2.y;
        acc[3][2 * j]     += A23.y * B2.x;
        acc[3][2 * j + 1] += A23.y * B2.y;
      }
    }
  }

  // epilogue: +bias, relu, store h[(nl*4096+p)*512 + oc]
#pragma unroll
  for (int i = 0; i < 4; ++i) {
    const int p = (y << 6) + ty4 + i;
    double* hrow = h + ((size_t)nl * 4096 + p) * 512 + ocg0;
#pragma unroll
    for (int j = 0; j < 4; ++j) {
      const int oc = (tx << 1) + (j << 5);
      double v0 = acc[i][2 * j]     + (double)bias[ocg0 + oc];
      double v1 = acc[i][2 * j + 1] + (double)bias[ocg0 + oc + 1];
      *(double2*)&hrow[oc] = make_double2(v0 > 0.0 ? v0 : 0.0,
                                          v1 > 0.0 ? v1 : 0.0);
    }
  }
}

// ---------------- K3: head (fp64) + decode + keys ----------------
// anchor corner constants as np.float32 values (promoted to f64 in use)
__device__ __constant__ float AC0[9] = {-37.254833996f, -82.509667992f, -173.019335984f,
                                        -56.f, -120.f, -248.f,
                                        -82.509667992f, -173.019335984f, -354.038671968f};
__device__ __constant__ float AC1[9] = {-82.509667992f, -173.019335984f, -354.038671968f,
                                        -56.f, -120.f, -248.f,
                                        -37.254833996f, -82.509667992f, -173.019335984f};
__device__ __constant__ float AC2[9] = {53.254833996f, 98.509667992f, 189.019335984f,
                                        72.f, 136.f, 264.f,
                                        98.509667992f, 189.019335984f, 370.038671968f};
__device__ __constant__ float AC3[9] = {98.509667992f, 189.019335984f, 370.038671968f,
                                        72.f, 136.f, 264.f,
                                        53.254833996f, 98.509667992f, 189.019335984f};

__global__ __launch_bounds__(256) void head_f64(
    const double* __restrict__ h,
    const float* __restrict__ sw, const float* __restrict__ sb,
    const float* __restrict__ lw, const float* __restrict__ lb,
    const int* __restrict__ imh, const int* __restrict__ imw,
    float* __restrict__ out_locs, float* __restrict__ out_scores,
    double* __restrict__ boxes, unsigned long long* __restrict__ ckeys, int base_n) {
  __shared__ double Wsh[128 * 54];   // [cc][o], 55.3 KB
  const int tid = threadIdx.x;
  const int gp = blockIdx.x * 256 + tid;   // chunk-local pixel
  const int nl = gp >> 12, p = gp & 4095;
  const int n = base_n + nl;

  double acc[54];
#pragma unroll
  for (int o = 0; o < 54; ++o) acc[o] = 0.0;

  for (int cb = 0; cb < 4; ++cb) {
    const int cbase = cb * 128;
    __syncthreads();
    for (int idx = tid; idx < 128 * 54; idx += 256) {
      int cc = idx / 54;
      int o  = idx - cc * 54;
      int c  = cbase + cc;
      float wv = (o < 18) ? sw[o * 512 + c] : lw[(o - 18) * 512 + c];
      Wsh[idx] = (double)wv;
    }
    __syncthreads();
    const double* hp = h + (size_t)gp * 512 + cbase;
    for (int cc = 0; cc < 128; ++cc) {
      double hv = hp[cc];
      const double2* wp = (const double2*)&Wsh[cc * 54];
#pragma unroll
      for (int oo = 0; oo < 27; ++oo) {
        double2 w2 = wp[oo];
        acc[oo * 2]     += w2.x * hv;
        acc[oo * 2 + 1] += w2.y * hv;
      }
    }
  }

  double sc[18], lcv[36];
#pragma unroll
  for (int j = 0; j < 18; ++j) sc[j] = acc[j] + (double)sb[j];
#pragma unroll
  for (int j = 0; j < 36; ++j) lcv[j] = acc[18 + j] + (double)lb[j];

  // continuous outputs (fp32)
  {
    size_t lo = (size_t)n * 147456 + (size_t)p * 36;
#pragma unroll
    for (int j = 0; j < 36; ++j) out_locs[lo + j] = (float)lcv[j];
    size_t so = (size_t)n * 73728 + (size_t)p * 18;
#pragma unroll
    for (int j = 0; j < 18; ++j) out_scores[so + j] = (float)sc[j];
  }

  // decode / clip / size-filter / key (all fp64, np op order)
  const double Hc = (double)imh[0], Wc = (double)imw[0];
  const double ys = (double)(p >> 6) * 16.0;
  const double xs = (double)(p & 63) * 16.0;
#pragma unroll
  for (int a = 0; a < 9; ++a) {
    // anchors are fp32 values (np.float32 in reference) promoted to f64:
    double a0 = (double)(float)((float)ys + AC0[a]);
    double a1 = (double)(float)((float)xs + AC1[a]);
    double a2 = (double)(float)((float)ys + AC2[a]);
    double a3 = (double)(float)((float)xs + AC3[a]);
    double ah = a2 - a0, aw = a3 - a1;
    double acy = a0 + 0.5 * ah;
    double acx = a1 + 0.5 * aw;
    double dy = lcv[a * 4 + 0], dx = lcv[a * 4 + 1], dh = lcv[a * 4 + 2], dw = lcv[a * 4 + 3];
    double cy = dy * ah + acy;
    double cx = dx * aw + acx;
    double bh = exp(dh) * ah;
    double bw = exp(dw) * aw;
    double y0 = cy - 0.5 * bh, x0 = cx - 0.5 * bw;
    double y1 = cy + 0.5 * bh, x1 = cx + 0.5 * bw;
    y0 = fmin(fmax(y0, 0.0), Hc); x0 = fmin(fmax(x0, 0.0), Wc);
    y1 = fmin(fmax(y1, 0.0), Hc); x1 = fmin(fmax(x1, 0.0), Wc);
    bool valid = ((y1 - y0) >= 16.0) && ((x1 - x0) >= 16.0);
    int bi = p * 9 + a;
    double* bq = boxes + ((size_t)n * NANCH + bi) * 4;
    bq[0] = y0; bq[1] = x0; bq[2] = y1; bq[3] = x1;
    double fgm = valid ? sc[a * 2 + 1] : -HUGE_VAL;
    unsigned long long u = (unsigned long long)__double_as_longlong(fgm);
    unsigned long long key = (u >> 63) ? ~u : (u | 0x8000000000000000ULL);
    ckeys[(size_t)n * NANCH + bi] = key;
  }
}

// ---------------- K4: radix-select pivot (64-bit) + bitonic sort top-2000 ----------------
__global__ __launch_bounds__(1024) void topk_kernel(
    const unsigned long long* __restrict__ ckeys, const double* __restrict__ boxes,
    double* __restrict__ bsort, int* __restrict__ fin) {
  __shared__ unsigned int hist[256];
  __shared__ unsigned long long srtk[2048];
  __shared__ int srti[2048];
  __shared__ unsigned long long Psh;
  __shared__ int tsh, cnt;
  const int n = blockIdx.x, tid = threadIdx.x;
  const unsigned long long* ck = ckeys + (size_t)n * NANCH;
  if (tid == 0) { tsh = PRE; Psh = 0ULL; }
  __syncthreads();
  for (int byte = 7; byte >= 0; --byte) {
    if (tid < 256) hist[tid] = 0u;
    __syncthreads();
    const int sh = byte * 8;
    const unsigned long long pref = Psh;
    for (int i = tid; i < NANCH; i += 1024) {
      unsigned long long v = ck[i];
      bool ok = (byte == 7) || ((v >> (sh + 8)) == pref);
      if (ok) atomicAdd(&hist[(unsigned)(v >> sh) & 255u], 1u);
    }
    __syncthreads();
    if (tid == 0) {
      int t = tsh, cum = 0, bsel = 0;
      for (int b = 255; b >= 0; --b) {
        int c = (int)hist[b];
        if (cum + c >= t) { bsel = b; tsh = t - cum; break; }
        cum += c;
      }
      Psh = (Psh << 8) | (unsigned long long)(unsigned)bsel;
    }
    __syncthreads();
  }
  const unsigned long long P = Psh;
  if (tid == 0) cnt = 0;
  for (int i = tid; i < 2048; i += 1024) { srtk[i] = 0ULL; srti[i] = 0; }
  __syncthreads();
  for (int i = tid; i < NANCH; i += 1024) {
    unsigned long long v = ck[i];
    if (v >= P) {
      int pos = atomicAdd(&cnt, 1);
      if (pos < 2048) { srtk[pos] = v; srti[pos] = i; }
    }
  }
  __syncthreads();
  // bitonic sort descending on keys (unique; pads=0 sort last)
  for (int k = 2; k <= 2048; k <<= 1) {
    for (int j = k >> 1; j > 0; j >>= 1) {
      for (int idx = tid; idx < 2048; idx += 1024) {
        int pr = idx ^ j;
        if (pr > idx) {
          unsigned long long a = srtk[idx], b = srtk[pr];
          bool up = (idx & k) == 0;
          if (up ? (a < b) : (a > b)) {
            srtk[idx] = b; srtk[pr] = a;
            int ti = srti[idx]; srti[idx] = srti[pr]; srti[pr] = ti;
          }
        }
      }
      __syncthreads();
    }
  }
  // gather boxes (f64) + finite flags
  const double* bsrc = boxes + (size_t)n * NANCH * 4;
  double* bdst = bsort + (size_t)n * 2048 * 4;
  for (int r = tid; r < PRE; r += 1024) {
    int bi = srti[r];
    fin[n * 2048 + r] = (srtk[r] > KEY_NEGINF) ? 1 : 0;
    bdst[r * 4 + 0] = bsrc[(size_t)bi * 4 + 0];
    bdst[r * 4 + 1] = bsrc[(size_t)bi * 4 + 1];
    bdst[r * 4 + 2] = bsrc[(size_t)bi * 4 + 2];
    bdst[r * 4 + 3] = bsrc[(size_t)bi * 4 + 3];
  }
}

// ---------------- K5: suppression bitmasks, fp64 IoU (np op order) ----------------
__global__ __launch_bounds__(256) void mask_kernel(
    const double* __restrict__ bsort, unsigned long long* __restrict__ masks) {
  __shared__ double bb[PRE * 4];   // 64 KB
  const int ib = blockIdx.x, n = blockIdx.y;
  const double2* src = (const double2*)(bsort + (size_t)n * 2048 * 4);
  for (int i = threadIdx.x; i < PRE * 2; i += 256) ((double2*)bb)[i] = src[i];
  __syncthreads();
  const int i = ib * 64 + (threadIdx.x >> 2);
  if (i >= PRE) return;
  const double ay0 = bb[i * 4], ax0 = bb[i * 4 + 1], ay1 = bb[i * 4 + 2], ax1 = bb[i * 4 + 3];
  const double aarea = (ay1 - ay0) * (ax1 - ax0);
  unsigned long long* mrow = masks + ((size_t)n * 2048 + i) * 32;
#pragma unroll
  for (int k = 0; k < 8; ++k) {
    const int w = (threadIdx.x & 3) + k * 4;
    unsigned long long m = 0ULL;
    for (int b = 0; b < 64; ++b) {
      int j = w * 64 + b;
      if (j < PRE) {
        double by0 = bb[j * 4], bx0 = bb[j * 4 + 1], by1 = bb[j * 4 + 2], bx1 = bb[j * 4 + 3];
        double ty = fmax(ay0, by0), tx = fmax(ax0, bx0);
        double ry = fmin(ay1, by1), rx = fmin(ax1, bx1);
        double ih = fmax(ry - ty, 0.0);
        double iw = fmax(rx - tx, 0.0);
        double inter = ih * iw;
        double barea = (by1 - by0) * (bx1 - bx0);
        double iou = inter / (aarea + barea - inter + 1e-9);
        if (iou > 0.7) m |= (1ULL << b);
      }
    }
    mrow[w] = m;
  }
}

// ---------------- K6: greedy scan, first-300-kept, write rois fp32 ----------------
__global__ void scan_kernel(const unsigned long long* __restrict__ masks,
                            const double* __restrict__ bsort, const int* __restrict__ fin,
                            float* __restrict__ out_rois, float* __restrict__ out_inds) {
  const int n = blockIdx.x, lane = threadIdx.x;
  const unsigned long long* mrow = masks + (size_t)n * 2048 * 32;
  unsigned long long rem = 0ULL;
  if (lane < 32) {
    unsigned long long fw = 0ULL;
    for (int b = 0; b < 64; ++b) {
      int i = (lane << 6) + b;
      if (i < PRE && fin[n * 2048 + i]) fw |= (1ULL << b);
    }
    rem = ~fw;
  }
  __shared__ int kept[POST];
  int kcnt = 0;
  for (int i = 0; i < PRE; ++i) {
    unsigned long long w = __shfl(rem, i >> 6);
    if (!((w >> (i & 63)) & 1ULL)) {
      if (lane == 0 && kcnt < POST) kept[kcnt] = i;
      ++kcnt;
      if (kcnt == POST) break;
      if (lane < 32) rem |= mrow[(size_t)i * 32 + lane];
    }
  }
  __syncthreads();
  const double* bs = bsort + (size_t)n * 2048 * 4;
  for (int r = lane; r < POST; r += 64) {
    double b0 = 0, b1 = 0, b2 = 0, b3 = 0;
    if (r < kcnt) {
      const double* q = bs + (size_t)kept[r] * 4;
      b0 = q[0]; b1 = q[1]; b2 = q[2]; b3 = q[3];
    }
    size_t o = ((size_t)n * POST + r) * 4;
    out_rois[o + 0] = (float)b0;
    out_rois[o + 1] = (float)b1;
    out_rois[o + 2] = (float)b2;
    out_rois[o + 3] = (float)b3;
    out_inds[n * POST + r] = (float)n;
  }
}

// ---------------- launch ----------------
extern "C" void kernel_launch(void* const* d_in, const int* in_sizes, int n_in,
                              void* d_out, int out_size, void* d_ws, size_t ws_size,
                              hipStream_t stream) {
  const float* x   = (const float*)d_in[0];
  const float* c1w = (const float*)d_in[1];
  const float* c1b = (const float*)d_in[2];
  const float* sw  = (const float*)d_in[3];
  const float* sb  = (const float*)d_in[4];
  const float* lw  = (const float*)d_in[5];
  const float* lb  = (const float*)d_in[6];
  const int* imh = (const int*)d_in[7];
  const int* imw = (const int*)d_in[8];
  float* out = (float*)d_out;

  // fixed ws ~26.0 MB; per-image (xpad f32 + h f64) ~25.7 MB
  int G = (ws_size >= 235000000ULL) ? 8
        : (ws_size >= 131000000ULL) ? 4
        : (ws_size >=  79000000ULL) ? 2 : 1;

  char* ws = (char*)d_ws;
  size_t off = 0;
  float* wtb   = (float*)(ws + off);  off += 9ULL * 512 * 512 * 4;
  float* xpad  = (float*)(ws + off);  off += (size_t)G * SZ_XPAD1;
  double* hbuf = (double*)(ws + off); off += (size_t)G * SZ_H1;
  double* boxes = (double*)(ws + off); off += 8ULL * NANCH * 4 * 8;
  unsigned long long* ckeys = (unsigned long long*)(ws + off); off += 8ULL * NANCH * 8;
  double* bsortd = (double*)(ws + off); off += 8ULL * 2048 * 4 * 8;
  int* fin = (int*)(ws + off); off += 8ULL * 2048 * 4;
  unsigned long long* masks = (unsigned long long*)(ws + off); off += 8ULL * 2048 * 32 * 8;

  float* out_locs   = out;                 // 8*36864*4
  float* out_scores = out + 1179648;       // 8*36864*2
  float* out_rois   = out + 1769472;       // 2400*4
  float* out_inds   = out + 1779072;       // 2400

  hipMemsetAsync(xpad, 0, (size_t)G * SZ_XPAD1, stream);
  wt_kernel<<<9216, 256, 0, stream>>>(c1w, wtb);
  for (int c = 0; c < NIMG / G; ++c) {
    pad_kernel<<<dim3(16, 512, G), 256, 0, stream>>>(x + (size_t)c * G * 512 * 4096, xpad);
    conv3_f64<<<dim3(4, 64, G), 256, 0, stream>>>(xpad, wtb, c1b, hbuf);
    head_f64<<<16 * G, 256, 0, stream>>>(hbuf, sw, sb, lw, lb, imh, imw,
                                         out_locs, out_scores, boxes, ckeys, c * G);
  }
  topk_kernel<<<8, 1024, 0, stream>>>(ckeys, boxes, bsortd, fin);
  mask_kernel<<<dim3(32, 8), 256, 0, stream>>>(bsortd, masks);
  scan_kernel<<<8, 64, 0, stream>>>(masks, bsortd, fin, out_rois, out_inds);
}